// Round 4
// baseline (404.722 us; speedup 1.0000x reference)
//
#include <hip/hip_runtime.h>
#include <cstdint>

// YOLO head decode: [B, 3*86, 76, 76] fp32 -> [B, 3*76*76, 86] fp32
// c0: (sig(v)+i)*8, c1: (sig(v)+j)*8, c2: exp(v)*aw, c3: exp(v)*ah, c>=4: sig(v)
//
// v5: NO LDS, NO barriers. lane = spatial position; each lane builds its own
// 86-float output row in registers across 4 channel passes (~22 regs live).
// Reads: in[c*SP + s] -> 256B/instr fully coalesced (granularity measured
// equivalent to 512B in v3/v4). Channel index is compile-time per unrolled
// iteration -> the c<4 special cases fold away, zero runtime divergence.
// Stores: 8B-aligned float2 pieces of the lane's contiguous 344B row; all
// pieces of each 64B line are issued back-to-back by one wave -> L2 sector
// write-combining (no RFO on CDNA) reassembles full lines.
// This deletes every shared suspect from v1-v4 except the raw R/W DRAM mix:
// LDS bank conflicts (provably >=8-way for any pad), the vmcnt+barrier phase
// serialization, and inter-block LDS reuse gaps.

#define GDIM 76
#define SP   (GDIM * GDIM)   // 5776
#define NCH  86
#define NANC 3
#define TPB  256

typedef float v2f __attribute__((ext_vector_type(2)));

__device__ __forceinline__ float fsig(float x) {
    return __builtin_amdgcn_rcpf(1.0f + __expf(-x));
}

template<int C0, int NC>
__device__ __forceinline__ void decode_pass(
    const float* __restrict__ inp, float* __restrict__ orow,
    float gx, float gy, float aw, float ah) {
    float r[NC];
    // issue all loads (independent, coalesced 256B per wave instr)
    #pragma unroll
    for (int i = 0; i < NC; ++i)
        r[i] = inp[(size_t)(C0 + i) * SP];
    // transform: channel is a compile-time constant per iteration
    #pragma unroll
    for (int i = 0; i < NC; ++i) {
        const int c = C0 + i;
        const float x = r[i];
        if      (c == 0) r[i] = (fsig(x) + gx) * 8.0f;
        else if (c == 1) r[i] = (fsig(x) + gy) * 8.0f;
        else if (c == 2) r[i] = __expf(x) * aw;
        else if (c == 3) r[i] = __expf(x) * ah;
        else             r[i] = fsig(x);
    }
    // store as 8B-aligned float2 pieces of this lane's row
    #pragma unroll
    for (int p = 0; p < NC / 2; ++p) {
        v2f t;
        t.x = r[2 * p];
        t.y = r[2 * p + 1];
        *(v2f*)(orow + C0 + 2 * p) = t;
    }
}

__global__ __launch_bounds__(TPB, 6) void yolo_decode_kernel(
    const float* __restrict__ in, float* __restrict__ out) {
    const int s = blockIdx.x * TPB + threadIdx.x;   // spatial position (lane-major)
    const int a = blockIdx.y;                       // anchor 0..2
    const int b = blockIdx.z;                       // batch
    if (s >= SP) return;                            // tail block guard

    const float aw = (a == 0) ? 116.0f : (a == 1) ? 156.0f : 373.0f;
    const float ah = (a == 0) ?  90.0f : (a == 1) ? 198.0f : 326.0f;

    const float* inp = in + (size_t)((b * NANC + a) * NCH) * SP + s;
    float* orow = out + ((size_t)(b * NANC + a) * SP + (size_t)s) * NCH;

    const float gx = (float)(s % GDIM);
    const float gy = (float)(s / GDIM);

    decode_pass< 0, 22>(inp, orow, gx, gy, aw, ah);
    decode_pass<22, 22>(inp, orow, gx, gy, aw, ah);
    decode_pass<44, 22>(inp, orow, gx, gy, aw, ah);
    decode_pass<66, 20>(inp, orow, gx, gy, aw, ah);
}

extern "C" void kernel_launch(void* const* d_in, const int* in_sizes, int n_in,
                              void* d_out, int out_size, void* d_ws, size_t ws_size,
                              hipStream_t stream) {
    const float* in = (const float*)d_in[0];
    float* out = (float*)d_out;
    const int B = in_sizes[0] / (NANC * NCH * SP);   // 32
    dim3 grid((SP + TPB - 1) / TPB, NANC, B);        // (23, 3, 32)
    yolo_decode_kernel<<<grid, TPB, 0, stream>>>(in, out);
}

// Round 5
// 332.872 us; speedup vs baseline: 1.2158x; 1.2158x over previous
//
#include <hip/hip_runtime.h>
#include <cstdint>

// YOLO head decode: [B, 3*86, 76, 76] fp32 -> [B, 3*76*76, 86] fp32
// c0: (sig(v)+i)*8, c1: (sig(v)+j)*8, c2: exp(v)*aw, c3: exp(v)*ah, c>=4: sig(v)
//
// v6: persistent blocks + XCD-bijective swizzle + double-buffered LDS pipeline.
// Keeps everything v4 proved: transform-at-load (channel uniform per 16-lane
// group), output-layout LDS tile, wave-linear float4 plain stores (v5 showed
// per-lane row stores break L2 line assembly: WRITE_SIZE +30%).
// New: 768 persistent blocks; block swz owns ~11 CONSECUTIVE tiles so its
// writes form one ~500KB linear stream and its reads 86 linear ~6KB streams
// (vs 512B fragments). XCD swizzle gives each XCD a contiguous 1/8 of the
// tensor. Pipeline: loads for tile t+1 issue before stores of tile t ->
// reads+writes continuously in flight, no phase-bunched R/W oscillation.

#define GDIM 76
#define SP   (GDIM * GDIM)          // 5776
#define NCH  86
#define NANC 3
#define TS   64                     // spatial positions per tile
#define TPB  256
#define NV   (NCH * TS / 4)         // 1376 float4 per full tile
#define NCHUNK ((SP + TS - 1) / TS) // 91
#define NXCD 8
#define NBLOCKS 768                 // 256 CUs x 3 resident blocks

typedef float v4f __attribute__((ext_vector_type(4)));

__device__ __forceinline__ float fsig(float x) {
    return __builtin_amdgcn_rcpf(1.0f + __expf(-x));
}

__global__ __launch_bounds__(TPB) void yolo_decode_kernel(
    const float* __restrict__ in, float* __restrict__ out, int ntiles) {
    __shared__ __align__(16) float tile[2][TS * NCH];   // 2 x 22016 B

    const int tid = threadIdx.x;
    // XCD-bijective swizzle: consecutive swz on one XCD -> contiguous tiles.
    const int swz = (blockIdx.x % NXCD) * (NBLOCKS / NXCD) + blockIdx.x / NXCD;

    // contiguous tile range for this block
    const int q   = ntiles / NBLOCKS;
    const int r   = ntiles - q * NBLOCKS;
    int t         = swz * q + (swz < r ? swz : r);
    const int cnt = q + (swz < r ? 1 : 0);
    if (cnt <= 0) return;

    // per-thread load/store geometry (tile-invariant)
    int ck[6], s4c[6];
    #pragma unroll
    for (int k = 0; k < 6; ++k) {
        const int idx = tid + (k << 8);
        ck[k]  = idx >> 4;            // channel (16 float4 per channel)
        s4c[k] = (idx & 15) << 2;     // spatial offset within tile
    }

    v4f vbuf[6];

    // ---- tile decode helpers (block-uniform scalars) ----
    #define DECODE_TILE(T, CH, A, BB, VAL)                       \
        { const unsigned tt = (unsigned)(T);                     \
          CH = (int)(tt % NCHUNK);                               \
          const unsigned sl = tt / NCHUNK;                       \
          A = (int)(sl % NANC); BB = (int)(sl / NANC);           \
          VAL = min(TS, SP - CH * TS); }

    #define LOAD_TILE(CH, A, BB, VAL)                                        \
        { const float* inp = in + ((size_t)((BB) * NANC + (A)) * NCH) * SP   \
                                + (size_t)(CH) * TS;                         \
          _Pragma("unroll")                                                  \
          for (int k = 0; k < 6; ++k) {                                      \
              const int idx = tid + (k << 8);                                \
              if (idx < NV && s4c[k] < (VAL))                                \
                  vbuf[k] = *(const v4f*)(inp + (size_t)ck[k] * SP + s4c[k]);\
          } }

    #define XFORM_WRITE(CH, A, VAL, DST)                                     \
        { const float aw = ((A) == 0) ? 116.0f : ((A) == 1) ? 156.0f : 373.0f;\
          const float ah = ((A) == 0) ?  90.0f : ((A) == 1) ? 198.0f : 326.0f;\
          const int s0 = (CH) * TS;                                          \
          _Pragma("unroll")                                                  \
          for (int k = 0; k < 6; ++k) {                                      \
              const int idx = tid + (k << 8);                                \
              const int c = ck[k], s4 = s4c[k];                              \
              if (idx < NV && s4 < (VAL)) {                                  \
                  v4f v = vbuf[k];                                           \
                  if (c >= 4) {                                              \
                      _Pragma("unroll")                                      \
                      for (int j = 0; j < 4; ++j) v[j] = fsig(v[j]);         \
                  } else if (c == 0) {                                       \
                      _Pragma("unroll")                                      \
                      for (int j = 0; j < 4; ++j)                            \
                          v[j] = (fsig(v[j]) +                               \
                                  (float)((s0 + s4 + j) % GDIM)) * 8.0f;     \
                  } else if (c == 1) {                                       \
                      _Pragma("unroll")                                      \
                      for (int j = 0; j < 4; ++j)                            \
                          v[j] = (fsig(v[j]) +                               \
                                  (float)((s0 + s4 + j) / GDIM)) * 8.0f;     \
                  } else {                                                   \
                      const float an = (c == 2) ? aw : ah;                   \
                      _Pragma("unroll")                                      \
                      for (int j = 0; j < 4; ++j) v[j] = __expf(v[j]) * an;  \
                  }                                                          \
                  _Pragma("unroll")                                          \
                  for (int j = 0; j < 4; ++j)                                \
                      (DST)[(s4 + j) * NCH + c] = v[j];                      \
              }                                                              \
          } }

    #define STORE_TILE(CH, A, BB, VAL, SRC)                                  \
        { v4f* outp = (v4f*)(out + ((size_t)((BB) * NANC + (A)) * SP         \
                                    + (size_t)(CH) * TS) * NCH);             \
          const int nvalid = ((VAL) * NCH) >> 2;                             \
          const v4f* lv = (const v4f*)(SRC);                                 \
          _Pragma("unroll")                                                  \
          for (int k = 0; k < 6; ++k) {                                      \
              const int v = tid + (k << 8);                                  \
              if (v < nvalid) outp[v] = lv[v];                               \
          } }

    // ---- prologue: stage first tile ----
    int chunk, a, b, valid;
    DECODE_TILE(t, chunk, a, b, valid);
    LOAD_TILE(chunk, a, b, valid);
    XFORM_WRITE(chunk, a, valid, tile[0]);
    __syncthreads();

    // ---- pipelined main loop ----
    int cur = 0;
    for (int i = 0; i < cnt; ++i) {
        int chunkN = 0, aN = 0, bN = 0, validN = 0;
        const bool nx = (i + 1 < cnt);          // block-uniform
        if (nx) {
            DECODE_TILE(t + 1, chunkN, aN, bN, validN);
            LOAD_TILE(chunkN, aN, bN, validN);  // global loads in flight...
        }
        STORE_TILE(chunk, a, b, valid, tile[cur]);   // ...while storing cur
        if (nx) XFORM_WRITE(chunkN, aN, validN, tile[cur ^ 1]);
        __syncthreads();
        cur ^= 1;
        ++t;
        chunk = chunkN; a = aN; b = bN; valid = validN;
    }

    #undef DECODE_TILE
    #undef LOAD_TILE
    #undef XFORM_WRITE
    #undef STORE_TILE
}

extern "C" void kernel_launch(void* const* d_in, const int* in_sizes, int n_in,
                              void* d_out, int out_size, void* d_ws, size_t ws_size,
                              hipStream_t stream) {
    const float* in = (const float*)d_in[0];
    float* out = (float*)d_out;
    const int B = in_sizes[0] / (NANC * NCH * SP);   // 32
    const int ntiles = NCHUNK * NANC * B;            // 8736
    yolo_decode_kernel<<<dim3(NBLOCKS), TPB, 0, stream>>>(in, out, ntiles);
}

// Round 6
// 318.354 us; speedup vs baseline: 1.2713x; 1.0456x over previous
//
#include <hip/hip_runtime.h>
#include <cstdint>

// YOLO head decode: [B, 3*86, 76, 76] fp32 -> [B, 3*76*76, 86] fp32
// c0: (sig(v)+i)*8, c1: (sig(v)+j)*8, c2: exp(v)*aw, c3: exp(v)*ah, c>=4: sig(v)
//
// v7: single-segment 1KB read requests. TS=256, 1024-thread blocks: one wave's
// float4 load = one channel's 256 floats = ONE contiguous page-aligned 1KB
// request (v1-v6 issued 2 discontiguous 512B segments per instr — the only
// remaining shape difference vs the 6.5 TB/s fill / 6.3 TB/s copy references).
// Keeps v4's proven structure: transform-at-load (branches now fully
// wave-uniform), output-layout LDS tile, wave-linear plain float4 stores,
// dispatch-order grid (v6 showed persistent+XCD swizzle widens the live
// address window: -8%). LDS 88KB -> 1 block/CU x 16 waves.
// Scatter would be 16-way bank-conflicted at this geometry (lane stride 344
// floats, period 4) -> T2-style XOR swizzle on 16B units, applied identically
// at scatter-write and linear-read; reader stays conflict-free, writer ~8-way
// (parity with v4). Swizzle never crosses a 128B block -> in-bounds.

#define GDIM 76
#define SP   (GDIM * GDIM)   // 5776
#define NCH  86
#define NANC 3
#define TS   256             // spatial positions per tile
#define TPB  1024            // threads per block
#define NV   (NCH * TS / 4)  // 5504 float4 per full tile
#define NCHUNK ((SP + TS - 1) / TS)  // 23 (tail: 144)

typedef float v4f __attribute__((ext_vector_type(4)));

__device__ __forceinline__ float fsig(float x) {
    return __builtin_amdgcn_rcpf(1.0f + __expf(-x));
}

// XOR-swizzle on 16B units, keyed by byte bits 9-11. Bijective; confined to
// each 128B block. Same function applied on write and read sides.
__device__ __forceinline__ int swz16(int byteoff) {
    return byteoff ^ (((byteoff >> 9) & 7) << 4);
}

__global__ __launch_bounds__(TPB) void yolo_decode_kernel(
    const float* __restrict__ in, float* __restrict__ out) {
    // Output-layout staging tile[s][c] (XOR-swizzled 16B units). 88064 B.
    __shared__ __align__(128) float tile[TS * NCH];

    const int tid   = threadIdx.x;
    const int chunk = blockIdx.x;        // 0..22  (fastest -> dispatch-order locality)
    const int a     = blockIdx.y;        // 0..2
    const int b     = blockIdx.z;        // 0..B-1
    const int s0    = chunk * TS;
    const int valid = min(TS, SP - s0);  // 256, or 144 tail (mult of 4)

    const float aw = (a == 0) ? 116.0f : (a == 1) ? 156.0f : 373.0f;
    const float ah = (a == 0) ?  90.0f : (a == 1) ? 198.0f : 326.0f;

    const float* inp = in + ((size_t)(b * (NANC * NCH) + a * NCH)) * SP + s0;

    // ---- phase 1a: loads. One wave = one channel = contiguous 1KB request ----
    v4f vbuf[6];
    #pragma unroll
    for (int k = 0; k < 6; ++k) {
        const int idx = tid + k * TPB;
        const int c   = idx >> 6;            // 64 float4 per channel
        const int s4  = (idx & 63) << 2;
        if (idx < NV && s4 < valid)
            vbuf[k] = *(const v4f*)(inp + (size_t)c * SP + s4);
    }

    // ---- phase 1b: transform (wave-uniform channel) + swizzled scatter ----
    #pragma unroll
    for (int k = 0; k < 6; ++k) {
        const int idx = tid + k * TPB;
        const int c   = idx >> 6;
        const int s4  = (idx & 63) << 2;
        if (idx < NV && s4 < valid) {
            v4f v = vbuf[k];
            if (c >= 4) {
                #pragma unroll
                for (int j = 0; j < 4; ++j) v[j] = fsig(v[j]);
            } else if (c == 0) {
                #pragma unroll
                for (int j = 0; j < 4; ++j)
                    v[j] = (fsig(v[j]) + (float)((s0 + s4 + j) % GDIM)) * 8.0f;
            } else if (c == 1) {
                #pragma unroll
                for (int j = 0; j < 4; ++j)
                    v[j] = (fsig(v[j]) + (float)((s0 + s4 + j) / GDIM)) * 8.0f;
            } else {  // c == 2 or 3
                const float an = (c == 2) ? aw : ah;
                #pragma unroll
                for (int j = 0; j < 4; ++j) v[j] = __expf(v[j]) * an;
            }
            #pragma unroll
            for (int j = 0; j < 4; ++j) {
                const int byteoff = ((s4 + j) * NCH + c) << 2;
                *(float*)((char*)tile + swz16(byteoff)) = v[j];
            }
        }
    }
    __syncthreads();

    // ---- phase 2: linear copy, swizzled LDS read -> wave-linear global store ----
    v4f* outp = (v4f*)(out + ((size_t)b * (NANC * SP) + (size_t)a * SP + (size_t)s0) * NCH);
    const int nvalid = (valid * NCH) >> 2;   // 5504 or 3096
    #pragma unroll
    for (int k = 0; k < 6; ++k) {
        const int v = tid + k * TPB;
        if (v < nvalid) {
            const v4f t = *(const v4f*)((const char*)tile + swz16(v << 4));
            outp[v] = t;
        }
    }
}

extern "C" void kernel_launch(void* const* d_in, const int* in_sizes, int n_in,
                              void* d_out, int out_size, void* d_ws, size_t ws_size,
                              hipStream_t stream) {
    const float* in = (const float*)d_in[0];
    float* out = (float*)d_out;
    const int B = in_sizes[0] / (NANC * NCH * SP);   // 32
    dim3 grid(NCHUNK, NANC, B);                      // (23, 3, 32)
    yolo_decode_kernel<<<grid, TPB, 0, stream>>>(in, out);
}